// Round 7
// baseline (698.477 us; speedup 1.0000x reference)
//
#include <hip/hip_runtime.h>
#include <math.h>

typedef __attribute__((ext_vector_type(8))) short s8v;   // 8 x bf16
typedef __attribute__((ext_vector_type(4))) short s4v;   // 4 x bf16
typedef __attribute__((ext_vector_type(4))) float f4v;   // 4 x f32
typedef __attribute__((ext_vector_type(16))) float f16v; // 16 x f32

static __device__ __forceinline__ unsigned short f2bf(float f) {
    union { float f; unsigned int u; } v; v.f = f;
    unsigned int r = v.u + 0x7fffu + ((v.u >> 16) & 1u);   // RNE
    return (unsigned short)(r >> 16);
}
static __device__ __forceinline__ float bf2f(unsigned short h) {
    union { unsigned int u; float f; } t; t.u = ((unsigned int)h) << 16;
    return t.f;
}

// ---------- fused: weight hi/lo split + G0 = Wh0 @ W_in ----------
__global__ void conv_g0(const float* __restrict__ Win, const float* __restrict__ Wh,
                        const float* __restrict__ Wout,
                        unsigned short* __restrict__ whi, unsigned short* __restrict__ wlo,
                        unsigned short* __restrict__ G0hi, unsigned short* __restrict__ G0lo,
                        unsigned short* __restrict__ G0F) {
    if (blockIdx.x < 3328) {
        int i = blockIdx.x * 256 + threadIdx.x;
        float v;
        if (i < 32768)       v = Win[i];
        else if (i < 819200) v = Wh[i - 32768];
        else                 v = Wout[i - 819200];
        unsigned short h = f2bf(v);
        whi[i] = h;
        wlo[i] = f2bf(v - bf2f(h));
    } else {
        int i = (blockIdx.x - 3328) * 4 + (threadIdx.x >> 6);   // 0..511 (hidden)
        int j = threadIdx.x & 63;                               // 0..63  (d)
        float acc = 0.f;
        for (int k = 0; k < 512; ++k)
            acc = fmaf(Wh[i * 512 + k], Win[k * 64 + j], acc);
        unsigned short h = f2bf(acc);
        G0hi[i * 64 + j] = h;
        G0lo[i * 64 + j] = f2bf(acc - bf2f(h));
        int sl = ((i >> 4) * 2 + (j >> 5)) * 64 + (j & 31) + 32 * ((i >> 3) & 1);
        G0F[(size_t)sl * 8 + (i & 7)] = h;
    }
}

// ================= shared GEMM bodies (R18-validated; m0/n0 parameters) =================
// fp32 body: mask-PRODUCING chain must stay fp32 (R17 lesson: 3-term bf16 preact
// error ~2e-4 flips ~900 masks -> h_dot absmax 0.14).

#define DF_LOAD(k0)                                                              \
    {                                                                            \
        _Pragma("unroll")                                                        \
        for (int r = 0; r < 2; ++r) {                                            \
            int idx = tid + r * 512;                                             \
            int row = idx >> 3, kq = (idx & 7) * 4;                              \
            xr[r] = *(const float4*)(X + (size_t)(m0 + row) * ldx + (k0) + kq);  \
        }                                                                        \
        {                                                                        \
            int row = tid >> 3, kq = (tid & 7) * 4;                              \
            wr = *(const float4*)(W + (size_t)(n0 + row) * ldw + (k0) + kq);     \
        }                                                                        \
    }
#define DF_STASH()                                                               \
    {                                                                            \
        _Pragma("unroll")                                                        \
        for (int r = 0; r < 2; ++r) {                                            \
            int idx = tid + r * 512;                                             \
            int row = idx >> 3, kq = (idx & 7) * 4;                              \
            Xs[kq + 0][row] = xr[r].x; Xs[kq + 1][row] = xr[r].y;                \
            Xs[kq + 2][row] = xr[r].z; Xs[kq + 3][row] = xr[r].w;                \
        }                                                                        \
        {                                                                        \
            int row = tid >> 3, kq = (tid & 7) * 4;                              \
            Ws[kq + 0][row] = wr.x; Ws[kq + 1][row] = wr.y;                      \
            Ws[kq + 2][row] = wr.z; Ws[kq + 3][row] = wr.w;                      \
        }                                                                        \
    }

static __device__ __forceinline__ void dual_fp32_body(
    unsigned char* lds, const float* __restrict__ X, int ldx,
    const float* __restrict__ W, int ldw, const float* __restrict__ bias,
    float* __restrict__ C, int ldc, unsigned char* __restrict__ maskOut,
    const unsigned char* __restrict__ maskMul, int K, int N, int mode,
    int m0, int n0)
{
    const int tid = threadIdx.x;
    float (*Xs)[132] = (float(*)[132])lds;                 // 16896 B
    float (*Ws)[68]  = (float(*)[68])(lds + 16896);        // 8704 B
    const int tx = tid & 15, ty = tid >> 4;                // ty 0..31
    float acc[4][4] = {};
    float4 xr[2], wr;

    DF_LOAD(0);
    DF_STASH();
    __syncthreads();

    for (int k0 = 0; k0 < K; k0 += 32) {
        bool last = (k0 + 32 >= K);
        if (!last) DF_LOAD(k0 + 32);
        #pragma unroll
        for (int kk = 0; kk < 32; ++kk) {
            float4 a0 = *(const float4*)&Xs[kk][ty * 4];
            float4 b0 = *(const float4*)&Ws[kk][tx * 4];
            float av[4] = {a0.x, a0.y, a0.z, a0.w};
            float bv[4] = {b0.x, b0.y, b0.z, b0.w};
            #pragma unroll
            for (int i = 0; i < 4; ++i)
                #pragma unroll
                for (int j = 0; j < 4; ++j)
                    acc[i][j] = fmaf(av[i], bv[j], acc[i][j]);
        }
        __syncthreads();
        if (!last) {
            DF_STASH();
            __syncthreads();
        }
    }

    float4 bb = {0, 0, 0, 0};
    if (mode & 1) bb = *(const float4*)(bias + n0 + tx * 4);
    const int c0 = n0 + tx * 4;
    #pragma unroll
    for (int i = 0; i < 4; ++i) {
        int r = m0 + ty * 4 + i;
        float v[4];
        #pragma unroll
        for (int j = 0; j < 4; ++j) {
            v[j] = acc[i][j];
            if (mode & 1) v[j] += ((const float*)&bb)[j];
        }
        if (mode & 8) {
            uchar4 mo;
            mo.x = v[0] > 0.0f; mo.y = v[1] > 0.0f; mo.z = v[2] > 0.0f; mo.w = v[3] > 0.0f;
            *(uchar4*)&maskOut[(size_t)r * N + c0] = mo;
        }
        if (mode & 16) {
            uchar4 mm = *(const uchar4*)&maskMul[(size_t)r * N + c0];
            v[0] *= mm.x; v[1] *= mm.y; v[2] *= mm.z; v[3] *= mm.w;
        }
        if (mode & 2) {
            #pragma unroll
            for (int j = 0; j < 4; ++j) v[j] = fmaxf(v[j], 0.0f);
        }
        if (mode & 4) {
            float4 st = {v[0], v[1], v[2], v[3]};
            *(float4*)(C + (size_t)r * ldc + c0) = st;
        }
    }
}
#undef DF_LOAD
#undef DF_STASH

#define DM_LOAD(k0)                                                                \
    {                                                                              \
        _Pragma("unroll")                                                          \
        for (int r = 0; r < 2; ++r) {                                              \
            int idx = tid + r * 512;                                               \
            int row = idx >> 3, kq = (idx & 7) * 4;                                \
            xr[r] = *(const float4*)(X + (size_t)(m0 + row) * ldx + (k0) + kq);    \
        }                                                                          \
        if (wload) {                                                               \
            int row = tid >> 2, kc = (tid & 3) * 8;                                \
            wh = *(const s8v*)(Whi + (size_t)(n0 + row) * ldw + (k0) + kc);        \
            wl = *(const s8v*)(Wlo + (size_t)(n0 + row) * ldw + (k0) + kc);        \
        }                                                                          \
    }
#define DM_STASH()                                                                 \
    {                                                                              \
        _Pragma("unroll")                                                          \
        for (int r = 0; r < 2; ++r) {                                              \
            int idx = tid + r * 512;                                               \
            int row = idx >> 3, kq = (idx & 7) * 4;                                \
            float a[4] = {xr[r].x, xr[r].y, xr[r].z, xr[r].w};                     \
            s4v hv, lv;                                                            \
            _Pragma("unroll")                                                      \
            for (int j = 0; j < 4; ++j) {                                          \
                unsigned short h = f2bf(a[j]);                                     \
                hv[j] = (short)h;                                                  \
                lv[j] = (short)f2bf(a[j] - bf2f(h));                               \
            }                                                                      \
            *(s4v*)&Xh[row * 40 + kq] = hv;                                        \
            *(s4v*)&Xl[row * 40 + kq] = lv;                                        \
        }                                                                          \
        if (wload) {                                                               \
            int row = tid >> 2, kc = (tid & 3) * 8;                                \
            *(s8v*)&Wsh[row * 40 + kc] = wh;                                       \
            *(s8v*)&Wsl[row * 40 + kc] = wl;                                       \
        }                                                                          \
    }

static __device__ __forceinline__ void dual_mfma_body(
    unsigned char* lds, const float* __restrict__ X, int ldx,
    const unsigned short* __restrict__ Whi, const unsigned short* __restrict__ Wlo, int ldw,
    const float* __restrict__ bias, float* __restrict__ C, int ldc,
    unsigned char* __restrict__ maskOut, const unsigned char* __restrict__ maskMul,
    int K, int N, int mode, int m0, int n0)
{
    const int tid = threadIdx.x;
    unsigned short* Xh  = (unsigned short*)lds;            // 128*40 = 10240 B
    unsigned short* Xl  = (unsigned short*)(lds + 10240);  // 10240 B
    unsigned short* Wsh = (unsigned short*)(lds + 20480);  // 5120 B
    unsigned short* Wsl = (unsigned short*)(lds + 25600);  // 5120 B

    const int wave = tid >> 6, lane = tid & 63;
    const int q = lane >> 4, ln = lane & 15;
    const int wm = (wave & 3) * 32;      // m-offset (0..96)
    const int wn = (wave >> 2) * 32;     // n-offset (0/32)

    f4v acc[2][2];
    #pragma unroll
    for (int mt = 0; mt < 2; ++mt)
        #pragma unroll
        for (int nt = 0; nt < 2; ++nt)
            acc[mt][nt] = (f4v)(0.0f);

    float4 xr[2];
    s8v wh, wl;
    const bool wload = (tid < 256);

    DM_LOAD(0);
    DM_STASH();
    __syncthreads();

    for (int k0 = 0; k0 < K; k0 += 32) {
        bool last = (k0 + 32 >= K);
        if (!last) DM_LOAD(k0 + 32);

        s8v ah[2], al[2], bh[2], bl[2];
        #pragma unroll
        for (int mt = 0; mt < 2; ++mt) {
            int rowm = wm + mt * 16 + ln;
            ah[mt] = *(const s8v*)&Xh[rowm * 40 + q * 8];
            al[mt] = *(const s8v*)&Xl[rowm * 40 + q * 8];
        }
        #pragma unroll
        for (int nt = 0; nt < 2; ++nt) {
            int rown = wn + nt * 16 + ln;
            bh[nt] = *(const s8v*)&Wsh[rown * 40 + q * 8];
            bl[nt] = *(const s8v*)&Wsl[rown * 40 + q * 8];
        }
        #pragma unroll
        for (int mt = 0; mt < 2; ++mt)
            #pragma unroll
            for (int nt = 0; nt < 2; ++nt) {
                acc[mt][nt] = __builtin_amdgcn_mfma_f32_16x16x32_bf16(ah[mt], bh[nt], acc[mt][nt], 0, 0, 0);
                acc[mt][nt] = __builtin_amdgcn_mfma_f32_16x16x32_bf16(ah[mt], bl[nt], acc[mt][nt], 0, 0, 0);
                acc[mt][nt] = __builtin_amdgcn_mfma_f32_16x16x32_bf16(al[mt], bh[nt], acc[mt][nt], 0, 0, 0);
            }

        __syncthreads();
        if (!last) {
            DM_STASH();
            __syncthreads();
        }
    }

    // epilogue: C-layout col=lane&15, row=q*4+r (m89-verified)
    #pragma unroll
    for (int nt = 0; nt < 2; ++nt) {
        int n = n0 + wn + nt * 16 + ln;
        float bv = (mode & 1) ? bias[n] : 0.0f;
        #pragma unroll
        for (int mt = 0; mt < 2; ++mt) {
            int mbase = m0 + wm + mt * 16 + q * 4;
            #pragma unroll
            for (int r = 0; r < 4; ++r) {
                int m = mbase + r;
                float v = acc[mt][nt][r] + bv;
                if (mode & 8)  maskOut[(size_t)m * N + n] = (v > 0.0f) ? 1 : 0;
                if (mode & 16) v *= (float)maskMul[(size_t)m * N + n];
                if (mode & 2)  v = fmaxf(v, 0.0f);
                if (mode & 4)  C[(size_t)m * ldc + n] = v;
            }
        }
    }
}
#undef DM_LOAD
#undef DM_STASH

// ======== fused h0 + frag_pack: z=0 t-h0 fp32, z=1 z-h0 MFMA, z=2 frag_pack ========
__global__ __launch_bounds__(512) void h0_pack(
    const float* __restrict__ x, const float* __restrict__ Win,
    const unsigned short* __restrict__ WinH, const unsigned short* __restrict__ WinL,
    const float* __restrict__ bin, float* __restrict__ tA, float* __restrict__ zA,
    const unsigned short* __restrict__ whi,
    unsigned short* __restrict__ WhF, unsigned short* __restrict__ WoF)
{
    __shared__ __align__(16) unsigned char lds[30720];
    const int m0 = blockIdx.x * 128, n0 = blockIdx.y * 64;
    int z = blockIdx.z;
    if (z == 0)
        dual_fp32_body(lds, x, 192, Win, 64, bin, tA, 512, 0, 0, 64, 512, 1 | 4, m0, n0);
    else if (z == 1)
        dual_mfma_body(lds, x + 128, 192, WinH, WinL, 64, bin, zA, 512, 0, 0, 64, 512, 1 | 4, m0, n0);
    else {
        int i = (blockIdx.y * 32 + blockIdx.x) * 512 + threadIdx.x;   // s8v slot
        if (i < 65536) {
            int lane = i & 63, ks = (i >> 6) & 31, g32 = (i >> 11) & 15, s = i >> 15;
            int row = g32 * 32 + (lane & 31);
            int k   = ks * 16 + (lane >> 5) * 8;
            const unsigned short* src = whi + 294912 + (size_t)s * 262144 + row * 512 + k;
            *(s8v*)(WhF + (size_t)i * 8) = *(const s8v*)src;
        } else if (i < 65536 + 4096) {
            int j = i - 65536;
            int lane = j & 63, ks = (j >> 6) & 31, g32 = j >> 11;
            int row = g32 * 32 + (lane & 31);
            int k   = ks * 16 + (lane >> 5) * 8;
            const unsigned short* src = whi + 819200 + row * 512 + k;
            *(s8v*)(WoF + (size_t)j * 8) = *(const s8v*)src;
        }
    }
}

// ======== mixed dual GEMM (h1): z=0 fp32 t-branch, z=1 split-bf16 MFMA z-branch ========
__global__ __launch_bounds__(512) void gemm_dualM(
    const float* __restrict__ X0, const float* __restrict__ X1, int ldx,
    const float* __restrict__ W, int ldw,
    const unsigned short* __restrict__ Whi, const unsigned short* __restrict__ Wlo,
    const float* __restrict__ bias,
    float* __restrict__ C0, float* __restrict__ C1, int ldc,
    unsigned char* __restrict__ mo0, unsigned char* __restrict__ mo1,
    int K, int N, int mode)
{
    __shared__ __align__(16) unsigned char lds[30720];
    const int m0 = blockIdx.x * 128, n0 = blockIdx.y * 64;
    if (blockIdx.z == 0)
        dual_fp32_body(lds, X0, ldx, W, ldw, bias, C0, ldc, mo0, 0, K, N, mode, m0, n0);
    else
        dual_mfma_body(lds, X1, ldx, Whi, Wlo, ldw, bias, C1, ldc, mo1, 0, K, N, mode, m0, n0);
}

// ======== fused dual4: z=0 t-h(next), z=1 z-h(next), z=2 t-delta(prev), z=3 z-delta ====
__global__ __launch_bounds__(512) void gemm_dual4(
    const float* __restrict__ X0, const float* __restrict__ X1, int ldx,
    const float* __restrict__ Wn, const float* __restrict__ Wd, int ldw,
    const unsigned short* __restrict__ WnH, const unsigned short* __restrict__ WnL,
    const unsigned short* __restrict__ WdH, const unsigned short* __restrict__ WdL,
    const float* __restrict__ bn, const float* __restrict__ bd,
    float* __restrict__ C0, float* __restrict__ C1, int ldc,
    unsigned char* __restrict__ mot, unsigned char* __restrict__ moz,
    int K, int N)
{
    __shared__ __align__(16) unsigned char lds[30720];
    const int m0 = blockIdx.x * 128, n0 = blockIdx.y * 64;
    int z = blockIdx.z;
    if (z == 0)
        dual_fp32_body(lds, X0, ldx, Wn, ldw, bn, C0, ldc, 0, 0, K, N, 1 | 2 | 4, m0, n0);
    else if (z == 2)
        dual_fp32_body(lds, X0, ldx, Wd, ldw, bd, 0, ldc, mot, 0, K, N, 1 | 8, m0, n0);
    else if (z == 1)
        dual_mfma_body(lds, X1, ldx, WnH, WnL, ldw, bn, C1, ldc, 0, 0, K, N, 1 | 2 | 4, m0, n0);
    else
        dual_mfma_body(lds, X1, ldx, WdH, WdL, ldw, bd, 0, ldc, moz, 0, K, N, 1 | 8, m0, n0);
}

// ======== fused delta3 + V1: z=0 t-delta3 fp32, z=1 z-delta3 MFMA, z=2 V1 MFMA ========
__global__ __launch_bounds__(512) void d3v1(
    const float* __restrict__ tB, const float* __restrict__ zB, const float* __restrict__ x,
    const float* __restrict__ Wh2,
    const unsigned short* __restrict__ Wh2H, const unsigned short* __restrict__ Wh2L,
    const unsigned short* __restrict__ G0hi, const unsigned short* __restrict__ G0lo,
    const float* __restrict__ bh2, float* __restrict__ tA,
    unsigned char* __restrict__ mt3, unsigned char* __restrict__ mz3,
    const unsigned char* __restrict__ mt1)
{
    __shared__ __align__(16) unsigned char lds[30720];
    const int m0 = blockIdx.x * 128, n0 = blockIdx.y * 64;
    int z = blockIdx.z;
    if (z == 0)
        dual_fp32_body(lds, tB, 512, Wh2, 512, bh2, 0, 512, mt3, 0, 512, 512, 1 | 8, m0, n0);
    else if (z == 1)
        dual_mfma_body(lds, zB, 512, Wh2H, Wh2L, 512, bh2, 0, 512, mz3, 0, 512, 512, 1 | 8, m0, n0);
    else
        dual_mfma_body(lds, x + 64, 192, G0hi, G0lo, 64, 0, tA, 512, 0, mt1, 64, 512, 4 | 16, m0, n0);
}

// ======== single-plane MFMA GEMM — V3 (mask-consuming) ========
__global__ __launch_bounds__(512) void gemm_m1(
    const float* __restrict__ X, int ldx,
    const unsigned short* __restrict__ Whi, const unsigned short* __restrict__ Wlo, int ldw,
    float* __restrict__ C, int ldc,
    const unsigned char* __restrict__ maskMul,
    int K, int N, int mode)
{
    __shared__ __align__(16) unsigned char lds[30720];
    dual_mfma_body(lds, X, ldx, Whi, Wlo, ldw, 0, C, ldc, 0, maskMul, K, N, mode,
                   blockIdx.x * 128, blockIdx.y * 64);
}

// ======== all-MFMA 2-plane — fused finals ========
__global__ __launch_bounds__(512) void gemm_mm(
    const float* __restrict__ X0, const float* __restrict__ X1, int ldx,
    const unsigned short* __restrict__ Whi, const unsigned short* __restrict__ Wlo, int ldw,
    const float* __restrict__ bias,
    float* __restrict__ C0, float* __restrict__ C1, int ldc,
    int K, int N, int mode0, int mode1)
{
    __shared__ __align__(16) unsigned char lds[30720];
    const int m0 = blockIdx.x * 128, n0 = blockIdx.y * 64;
    if (blockIdx.z == 0)
        dual_mfma_body(lds, X0, ldx, Whi, Wlo, ldw, bias, C0, ldc, 0, 0, K, N, mode0, m0, n0);
    else
        dual_mfma_body(lds, X1, ldx, Whi, Wlo, ldw, bias, C1, ldc, 0, 0, K, N, mode1, m0, n0);
}

// ---------- zng (R20): 2 elements/block, 4 m-tiles/wave ----------
// waves 0-3 -> elem 0, waves 4-7 -> elem 1; each wave computes 128 output rows
// (4 m-tiles x 2 n-tiles = 8 MFMA/iter, 64 issue-cyc) -> 2-deep A prefetch lead
// ~260 cyc >= L2 latency. LDS 130KB -> 1 block/CU; __launch_bounds__(512,2) ->
// 256-reg cap (acc 128 AGPR + ~90 VGPR). Numerics identical to R16 zng.
// bx >= 2048: V2 tail blocks (backfill drain).
__global__ __launch_bounds__(512, 2) void zng_v2(
    const unsigned short* __restrict__ WhF,    // [2][16][32][64][8] frag-packed Wh1,Wh2
    const unsigned short* __restrict__ WoF,    // [2][32][64][8] frag-packed Wout
    const unsigned short* __restrict__ G0F,    // [32][2][64][8] frag-packed G0
    const unsigned char* __restrict__ mz1,
    const unsigned char* __restrict__ mz2,
    const unsigned char* __restrict__ mz3,
    float* __restrict__ out,                   // (4096,192), writes cols 128..191
    const float* __restrict__ tA,              // V1 output (V2 input)
    const unsigned short* __restrict__ Wh1H, const unsigned short* __restrict__ Wh1L,
    const unsigned char* __restrict__ mt2,
    float* __restrict__ zA)                    // V2 output
{
    __shared__ __align__(16) unsigned char ldsb[133120]; // 2x RtF(64KB) + 2x masks(1KB)

    if (blockIdx.x >= 2048) {
        int idx = blockIdx.x - 2048;           // 0..255
        dual_mfma_body(ldsb, tA, 512, Wh1H, Wh1L, 512, 0, zA, 512, 0, mt2,
                       512, 512, 4 | 16, (idx & 31) * 128, (idx >> 5) * 64);
        return;
    }

    unsigned short* RtF0 = (unsigned short*)ldsb;           // 65536 B elem0
    unsigned short* RtF1 = (unsigned short*)(ldsb + 65536); // 65536 B elem1
    unsigned char* m2s = ldsb + 131072;                     // [2][512]
    unsigned char* m3s = ldsb + 132096;                     // [2][512]

    const int b0  = blockIdx.x;     // two batch elements: 2*b0, 2*b0+1
    const int tid = threadIdx.x;

    #pragma unroll
    for (int e = 0; e < 2; ++e) {
        m2s[e * 512 + tid] = mz2[(size_t)(2 * b0 + e) * 512 + tid];
        m3s[e * 512 + tid] = mz3[(size_t)(2 * b0 + e) * 512 + tid];
    }

    // ---- setup: RtF_e = frag(mask1_e (.) G0^T); 256 threads per elem ----
    {
        const int e = tid >> 8, t256 = tid & 255;
        unsigned short* RtF = e ? RtF1 : RtF0;
        const unsigned char* mme = mz1 + (size_t)(2 * b0 + e) * 512;
        #pragma unroll
        for (int it = 0; it < 16; ++it) {
            int sl = it * 256 + t256;          // fragment slot 0..4095
            int ls = sl & 63;                  // lane within fragment
            int ks = sl >> 7;                  // k-step
            int k0 = ks * 16 + (ls >> 5) * 8;  // first k of this lane's 8 elems
            s8v g = *(const s8v*)(G0F + (size_t)sl * 8);
            unsigned int mlo = *(const unsigned int*)(mme + k0);
            unsigned int mhi = *(const unsigned int*)(mme + k0 + 4);
            s8v r;
            #pragma unroll
            for (int j = 0; j < 4; ++j) r[j] = ((mlo >> (8 * j)) & 1) ? g[j] : (short)0;
            #pragma unroll
            for (int j = 0; j < 4; ++j) r[4 + j] = ((mhi >> (8 * j)) & 1) ? g[4 + j] : (short)0;
            *(s8v*)(&RtF[(size_t)sl * 8]) = r;
        }
    }
    __syncthreads();

    const int lane = tid & 63, wave = tid >> 6;
    const int l31 = lane & 31, h = lane >> 5;
    const int we = wave >> 2;                  // element of this wave
    const int wq = wave & 3;                   // quarter (128 rows) within element
    unsigned short* RtF = we ? RtF1 : RtF0;

    // ---- 2 chained layers: R <- mask (.) (Wh @ R) ----
    for (int s = 0; s < 2; ++s) {
        // 4 m-tiles: g32 = wq*4 + mt
        const unsigned short* Ar = WhF + (size_t)s * 262144
                                 + (size_t)(wq * 4) * 16384 + lane * 8;

        f16v acc[4][2];
        #pragma unroll
        for (int mt = 0; mt < 4; ++mt)
            #pragma unroll
            for (int nt = 0; nt < 2; ++nt)
                acc[mt][nt] = (f16v)(0.0f);

        // 2-deep A prefetch (lead ~2 x 130cyc >= L2 latency), 1-deep B prefetch
        s8v aA[4], aB[4];
        #pragma unroll
        for (int mt = 0; mt < 4; ++mt) {
            aA[mt] = *(const s8v*)(Ar + (size_t)mt * 16384);
            aB[mt] = *(const s8v*)(Ar + (size_t)mt * 16384 + 512);
        }
        s8v b0c = *(const s8v*)&RtF[lane * 8];
        s8v b1c = *(const s8v*)&RtF[512 + lane * 8];

        #pragma unroll 4
        for (int ks = 0; ks < 32; ++ks) {
            int kf = ((ks + 2) & 31) * 512;           // A: wraps; redundant tail loads
            s8v aN[4];
            #pragma unroll
            for (int mt = 0; mt < 4; ++mt)
                aN[mt] = *(const s8v*)(Ar + (size_t)mt * 16384 + kf);
            int kb = ((ks + 1) & 31) * 1024;          // B: fragment-linear
            s8v b0n = *(const s8v*)&RtF[kb + lane * 8];
            s8v b1n = *(const s8v*)&RtF[kb + 512 + lane * 8];

            __builtin_amdgcn_s_setprio(1);
            #pragma unroll
            for (int mt = 0; mt < 4; ++mt) {
                acc[mt][0] = __builtin_amdgcn_mfma_f32_32x32x16_bf16(aA[mt], b0c, acc[mt][0], 0, 0, 0);
                acc[mt][1] = __builtin_amdgcn_mfma_f32_32x32x16_bf16(aA[mt], b1c, acc[mt][1], 0, 0, 0);
            }
            __builtin_amdgcn_s_setprio(0);

            #pragma unroll
            for (int mt = 0; mt < 4; ++mt) {
                aA[mt] = aB[mt];
                aB[mt] = aN[mt];
            }
            b0c = b0n; b1c = b1n;
        }
        __syncthreads();

        // ---- epilogue: mask, pack bf16, write new RtF (fragment order) ----
        const unsigned char* msk = ((s == 0) ? m2s : m3s) + we * 512;
        #pragma unroll
        for (int mt = 0; mt < 4; ++mt) {
            #pragma unroll
            for (int g = 0; g < 4; ++g) {
                int kk = wq * 128 + mt * 32 + g * 8 + h * 4;    // output k-row base
                int ks2 = wq * 8 + mt * 2 + (g >> 1);
                int khalf = g & 1;
                uchar4 mv = *(const uchar4*)&msk[kk];
                unsigned char mb[4] = {mv.x, mv.y, mv.z, mv.w};
                #pragma unroll
                for (int nt = 0; nt < 2; ++nt) {
                    s4v pk;
                    #pragma unroll
                    for (int r = 0; r < 4; ++r) {
                        float v = mb[r] ? acc[mt][nt][g * 4 + r] : 0.0f;
                        pk[r] = (short)f2bf(v);
                    }
                    *(s4v*)(&RtF[(ks2 * 2 + nt) * 512 + (l31 + 32 * khalf) * 8 + h * 4]) = pk;
                }
            }
        }
        __syncthreads();
    }

    // ---- final: Wout @ R, row norms; 2 waves per element (no barriers below) ----
    if (wq < 2) {
        const unsigned short* Wr = WoF + wq * 16384 + lane * 8;
        f16v a3[2];
        a3[0] = (f16v)(0.0f);
        a3[1] = (f16v)(0.0f);
        #pragma unroll 2
        for (int ks = 0; ks < 32; ++ks) {
            s8v af = *(const s8v*)(Wr + ks * 512);
            s8v bb0 = *(const s8v*)&RtF[ks * 1024 + lane * 8];
            s8v bb1 = *(const s8v*)&RtF[ks * 1024 + 512 + lane * 8];
            a3[0] = __builtin_amdgcn_mfma_f32_32x32x16_bf16(af, bb0, a3[0], 0, 0, 0);
            a3[1] = __builtin_amdgcn_mfma_f32_32x32x16_bf16(af, bb1, a3[1], 0, 0, 0);
        }
        // per-lane: rows wq*32 + g*8 + h*4 + r, cols (nt*32 + l31)
        float sq[16];
        #pragma unroll
        for (int i = 0; i < 16; ++i) {
            float v0 = a3[0][i], v1 = a3[1][i];
            sq[i] = fmaf(v0, v0, v1 * v1);
        }
        #pragma unroll
        for (int off = 1; off < 32; off <<= 1)
            #pragma unroll
            for (int i = 0; i < 16; ++i)
                sq[i] += __shfl_xor(sq[i], off, 64);
        if (l31 == 0) {
            #pragma unroll
            for (int g = 0; g < 4; ++g)
                #pragma unroll
                for (int r = 0; r < 4; ++r)
                    out[(size_t)(2 * b0 + we) * 192 + 128 + wq * 32 + g * 8 + h * 4 + r] = sqrtf(sq[g * 4 + r]);
        }
    }
}

// ---------- host ----------
extern "C" void kernel_launch(void* const* d_in, const int* in_sizes, int n_in,
                              void* d_out, int out_size, void* d_ws, size_t ws_size,
                              hipStream_t stream) {
    const float* x    = (const float*)d_in[0];
    const float* Win  = (const float*)d_in[1];
    const float* bin  = (const float*)d_in[2];
    const float* Wh   = (const float*)d_in[3];
    const float* bh   = (const float*)d_in[4];
    const float* Wout = (const float*)d_in[5];
    const float* bout = (const float*)d_in[6];
    float* out = (float*)d_out;

    char* ws = (char*)d_ws;
    unsigned short* whi  = (unsigned short*)(ws);                   // 1703936 B
    unsigned short* wlo  = (unsigned short*)(ws + 1703936);         // 1703936 B
    unsigned short* G0hi = (unsigned short*)(ws + 3407872);         // 65536 B
    unsigned short* G0lo = (unsigned short*)(ws + 3473408);         // 65536 B
    unsigned short* G0F  = (unsigned short*)(ws + 3538944);         // 65536 B (frag-packed)
    unsigned char*  masks = (unsigned char*)(ws + 3604480);         // 6 * 2 MB
    unsigned char* mt1 = masks + 0 * 2097152;
    unsigned char* mt2 = masks + 1 * 2097152;
    unsigned char* mt3 = masks + 2 * 2097152;
    unsigned char* mz1 = masks + 3 * 2097152;
    unsigned char* mz2 = masks + 4 * 2097152;
    unsigned char* mz3 = masks + 5 * 2097152;
    float* bufs = (float*)(ws + 3604480 + 12582912);                // 4 x 8 MB
    float* tA = bufs + 0 * 2097152;
    float* tB = bufs + 1 * 2097152;
    float* zA = bufs + 2 * 2097152;
    float* zB = bufs + 3 * 2097152;
    unsigned short* WhF = (unsigned short*)(ws + 49741824);         // 1048576 B
    unsigned short* WoF = (unsigned short*)(ws + 50790400);         // 65536 B

    // hi/lo plane offsets (elems): [Win@0 | Wh0@32768 | Wh1@294912 | Wh2@557056 | Wout@819200]
    const unsigned short* WinH  = whi,          *WinL  = wlo;
    const unsigned short* Wh0H  = whi + 32768,  *Wh0L  = wlo + 32768;
    const unsigned short* Wh1H  = whi + 294912, *Wh1L  = wlo + 294912;
    const unsigned short* Wh2H  = whi + 557056, *Wh2L  = wlo + 557056;
    const unsigned short* WoutH = whi + 819200, *WoutL = wlo + 819200;

    const float* Wh0 = Wh;
    const float* Wh1 = Wh + 262144;
    const float* Wh2 = Wh + 524288;
    const float* bh0 = bh, *bh1 = bh + 512, *bh2 = bh + 1024;

    // ---- setup ----
    conv_g0<<<dim3(3456), dim3(256), 0, stream>>>(Win, Wh, Wout, whi, wlo, G0hi, G0lo, G0F);
    h0_pack<<<dim3(32, 8, 3), dim3(512), 0, stream>>>(x, Win, WinH, WinL, bin, tA, zA,
                                                      whi, WhF, WoF);                              // h0 + frag_pack

    // ---- forward + delta chain (t fp32 for mask fidelity; z split-bf16 MFMA) ----
    gemm_dualM<<<dim3(32, 8, 2), dim3(512), 0, stream>>>(tA, zA, 512, Wh0, 512, Wh0H, Wh0L, bh0,
                                                         tB, zB, 512, 0, 0, 512, 512, 1 | 2 | 4);  // h1
    gemm_dual4<<<dim3(32, 8, 4), dim3(512), 0, stream>>>(tB, zB, 512, Wh1, Wh0, 512,
                                                         Wh1H, Wh1L, Wh0H, Wh0L, bh1, bh0,
                                                         tA, zA, 512, mt1, mz1, 512, 512);         // h2 + delta1
    gemm_dual4<<<dim3(32, 8, 4), dim3(512), 0, stream>>>(tA, zA, 512, Wh2, Wh1, 512,
                                                         Wh2H, Wh2L, Wh1H, Wh1L, bh2, bh1,
                                                         tB, zB, 512, mt2, mz2, 512, 512);         // h3 + delta2
    d3v1<<<dim3(32, 8, 3), dim3(512), 0, stream>>>(tB, zB, x, Wh2, Wh2H, Wh2L, G0hi, G0lo,
                                                   bh2, tA, mt3, mz3, mt1);                        // delta3 + V1

    // ---- zng (2048 blocks, 2 elems each) + V2 (256 tail blocks, backfill) ----
    zng_v2<<<dim3(2304), dim3(512), 0, stream>>>(WhF, WoF, G0F, mz1, mz2, mz3, out,
                                                 tA, Wh1H, Wh1L, mt2, zA);

    // ---- V3 ----
    gemm_m1<<<dim3(32, 8), dim3(512), 0, stream>>>(zA, 512, Wh2H, Wh2L, 512, zB, 512,
                                                   mt3, 512, 512, 4 | 16);                         // V3

    // ---- fused finals: h_out (t, cols 0..63, +bias) + h_dot (V3, cols 64..127) ----
    gemm_mm<<<dim3(32, 1, 2), dim3(512), 0, stream>>>(tB, zB, 512, WoutH, WoutL, 512, bout,
                                                      out, out + 64, 192, 512, 64, 1 | 4, 4);
}

// Round 8
// 614.036 us; speedup vs baseline: 1.1375x; 1.1375x over previous
//
#include <hip/hip_runtime.h>
#include <math.h>

typedef __attribute__((ext_vector_type(8))) short s8v;   // 8 x bf16
typedef __attribute__((ext_vector_type(4))) short s4v;   // 4 x bf16
typedef __attribute__((ext_vector_type(4))) float f4v;   // 4 x f32
typedef __attribute__((ext_vector_type(16))) float f16v; // 16 x f32

static __device__ __forceinline__ unsigned short f2bf(float f) {
    union { float f; unsigned int u; } v; v.f = f;
    unsigned int r = v.u + 0x7fffu + ((v.u >> 16) & 1u);   // RNE
    return (unsigned short)(r >> 16);
}
static __device__ __forceinline__ float bf2f(unsigned short h) {
    union { unsigned int u; float f; } t; t.u = ((unsigned int)h) << 16;
    return t.f;
}

// ---------- fused: weight hi/lo split + G0 = Wh0 @ W_in ----------
__global__ void conv_g0(const float* __restrict__ Win, const float* __restrict__ Wh,
                        const float* __restrict__ Wout,
                        unsigned short* __restrict__ whi, unsigned short* __restrict__ wlo,
                        unsigned short* __restrict__ G0hi, unsigned short* __restrict__ G0lo,
                        unsigned short* __restrict__ G0F) {
    if (blockIdx.x < 3328) {
        int i = blockIdx.x * 256 + threadIdx.x;
        float v;
        if (i < 32768)       v = Win[i];
        else if (i < 819200) v = Wh[i - 32768];
        else                 v = Wout[i - 819200];
        unsigned short h = f2bf(v);
        whi[i] = h;
        wlo[i] = f2bf(v - bf2f(h));
    } else {
        int i = (blockIdx.x - 3328) * 4 + (threadIdx.x >> 6);   // 0..511 (hidden)
        int j = threadIdx.x & 63;                               // 0..63  (d)
        float acc = 0.f;
        for (int k = 0; k < 512; ++k)
            acc = fmaf(Wh[i * 512 + k], Win[k * 64 + j], acc);
        unsigned short h = f2bf(acc);
        G0hi[i * 64 + j] = h;
        G0lo[i * 64 + j] = f2bf(acc - bf2f(h));
        int sl = ((i >> 4) * 2 + (j >> 5)) * 64 + (j & 31) + 32 * ((i >> 3) & 1);
        G0F[(size_t)sl * 8 + (i & 7)] = h;
    }
}

// ================= shared GEMM bodies =================
// fp32 body: mask-PRODUCING t-chain must stay fp32 (R17: bf16 preact error ~2e-4
// flips ~900 masks -> absmax 0.14).  R21: z-chain activations stored as bf16
// hi/lo PLANES (producer-side split; bit-identical MFMA inputs, 8x less
// conversion VALU than consumer-side split).

#define DF_LOAD(k0)                                                              \
    {                                                                            \
        _Pragma("unroll")                                                        \
        for (int r = 0; r < 2; ++r) {                                            \
            int idx = tid + r * 512;                                             \
            int row = idx >> 3, kq = (idx & 7) * 4;                              \
            xr[r] = *(const float4*)(X + (size_t)(m0 + row) * ldx + (k0) + kq);  \
        }                                                                        \
        {                                                                        \
            int row = tid >> 3, kq = (tid & 7) * 4;                              \
            wr = *(const float4*)(W + (size_t)(n0 + row) * ldw + (k0) + kq);     \
        }                                                                        \
    }
#define DF_STASH()                                                               \
    {                                                                            \
        _Pragma("unroll")                                                        \
        for (int r = 0; r < 2; ++r) {                                            \
            int idx = tid + r * 512;                                             \
            int row = idx >> 3, kq = (idx & 7) * 4;                              \
            Xs[kq + 0][row] = xr[r].x; Xs[kq + 1][row] = xr[r].y;                \
            Xs[kq + 2][row] = xr[r].z; Xs[kq + 3][row] = xr[r].w;                \
        }                                                                        \
        {                                                                        \
            int row = tid >> 3, kq = (tid & 7) * 4;                              \
            Ws[kq + 0][row] = wr.x; Ws[kq + 1][row] = wr.y;                      \
            Ws[kq + 2][row] = wr.z; Ws[kq + 3][row] = wr.w;                      \
        }                                                                        \
    }

static __device__ __forceinline__ void dual_fp32_body(
    unsigned char* lds, const float* __restrict__ X, int ldx,
    const float* __restrict__ W, int ldw, const float* __restrict__ bias,
    float* __restrict__ C, int ldc, unsigned char* __restrict__ maskOut,
    const unsigned char* __restrict__ maskMul, int K, int N, int mode,
    int m0, int n0)
{
    const int tid = threadIdx.x;
    float (*Xs)[132] = (float(*)[132])lds;                 // 16896 B
    float (*Ws)[68]  = (float(*)[68])(lds + 16896);        // 8704 B
    const int tx = tid & 15, ty = tid >> 4;                // ty 0..31
    float acc[4][4] = {};
    float4 xr[2], wr;

    DF_LOAD(0);
    DF_STASH();
    __syncthreads();

    for (int k0 = 0; k0 < K; k0 += 32) {
        bool last = (k0 + 32 >= K);
        if (!last) DF_LOAD(k0 + 32);
        #pragma unroll
        for (int kk = 0; kk < 32; ++kk) {
            float4 a0 = *(const float4*)&Xs[kk][ty * 4];
            float4 b0 = *(const float4*)&Ws[kk][tx * 4];
            float av[4] = {a0.x, a0.y, a0.z, a0.w};
            float bv[4] = {b0.x, b0.y, b0.z, b0.w};
            #pragma unroll
            for (int i = 0; i < 4; ++i)
                #pragma unroll
                for (int j = 0; j < 4; ++j)
                    acc[i][j] = fmaf(av[i], bv[j], acc[i][j]);
        }
        __syncthreads();
        if (!last) {
            DF_STASH();
            __syncthreads();
        }
    }

    float4 bb = {0, 0, 0, 0};
    if (mode & 1) bb = *(const float4*)(bias + n0 + tx * 4);
    const int c0 = n0 + tx * 4;
    #pragma unroll
    for (int i = 0; i < 4; ++i) {
        int r = m0 + ty * 4 + i;
        float v[4];
        #pragma unroll
        for (int j = 0; j < 4; ++j) {
            v[j] = acc[i][j];
            if (mode & 1) v[j] += ((const float*)&bb)[j];
        }
        if (mode & 8) {
            uchar4 mo;
            mo.x = v[0] > 0.0f; mo.y = v[1] > 0.0f; mo.z = v[2] > 0.0f; mo.w = v[3] > 0.0f;
            *(uchar4*)&maskOut[(size_t)r * N + c0] = mo;
        }
        if (mode & 16) {
            uchar4 mm = *(const uchar4*)&maskMul[(size_t)r * N + c0];
            v[0] *= mm.x; v[1] *= mm.y; v[2] *= mm.z; v[3] *= mm.w;
        }
        if (mode & 2) {
            #pragma unroll
            for (int j = 0; j < 4; ++j) v[j] = fmaxf(v[j], 0.0f);
        }
        if (mode & 4) {
            float4 st = {v[0], v[1], v[2], v[3]};
            *(float4*)(C + (size_t)r * ldc + c0) = st;
        }
    }
}
#undef DF_LOAD
#undef DF_STASH

// ---- shared MFMA epilogue: fp32-out (mode&4) and/or bf16 plane-out (mode&32) ----
static __device__ __forceinline__ void mfma_epi(
    f4v (&acc)[2][2], const float* __restrict__ bias,
    float* __restrict__ C, unsigned short* __restrict__ Ch, unsigned short* __restrict__ Cl,
    int ldc, unsigned char* __restrict__ maskOut, const unsigned char* __restrict__ maskMul,
    int N, int mode, int m0, int n0, int wm, int wn, int q, int ln)
{
    #pragma unroll
    for (int nt = 0; nt < 2; ++nt) {
        int n = n0 + wn + nt * 16 + ln;
        float bv = (mode & 1) ? bias[n] : 0.0f;
        #pragma unroll
        for (int mt = 0; mt < 2; ++mt) {
            int mbase = m0 + wm + mt * 16 + q * 4;
            #pragma unroll
            for (int r = 0; r < 4; ++r) {
                int m = mbase + r;
                float v = acc[mt][nt][r] + bv;
                if (mode & 8)  maskOut[(size_t)m * N + n] = (v > 0.0f) ? 1 : 0;
                if (mode & 16) v *= (float)maskMul[(size_t)m * N + n];
                if (mode & 2)  v = fmaxf(v, 0.0f);
                if (mode & 4)  C[(size_t)m * ldc + n] = v;
                if (mode & 32) {
                    unsigned short hh = f2bf(v);
                    Ch[(size_t)m * ldc + n] = hh;
                    Cl[(size_t)m * ldc + n] = f2bf(v - bf2f(hh));
                }
            }
        }
    }
}

// ---- fp32-input MFMA body (consumer-side split; used where input is raw fp32) ----
#define DM_LOAD(k0)                                                                \
    {                                                                              \
        _Pragma("unroll")                                                          \
        for (int r = 0; r < 2; ++r) {                                              \
            int idx = tid + r * 512;                                               \
            int row = idx >> 3, kq = (idx & 7) * 4;                                \
            xr[r] = *(const float4*)(X + (size_t)(m0 + row) * ldx + (k0) + kq);    \
        }                                                                          \
        if (wload) {                                                               \
            int row = tid >> 2, kc = (tid & 3) * 8;                                \
            wh = *(const s8v*)(Whi + (size_t)(n0 + row) * ldw + (k0) + kc);        \
            wl = *(const s8v*)(Wlo + (size_t)(n0 + row) * ldw + (k0) + kc);        \
        }                                                                          \
    }
#define DM_STASH()                                                                 \
    {                                                                              \
        _Pragma("unroll")                                                          \
        for (int r = 0; r < 2; ++r) {                                              \
            int idx = tid + r * 512;                                               \
            int row = idx >> 3, kq = (idx & 7) * 4;                                \
            float a[4] = {xr[r].x, xr[r].y, xr[r].z, xr[r].w};                     \
            s4v hv, lv;                                                            \
            _Pragma("unroll")                                                      \
            for (int j = 0; j < 4; ++j) {                                          \
                unsigned short h = f2bf(a[j]);                                     \
                hv[j] = (short)h;                                                  \
                lv[j] = (short)f2bf(a[j] - bf2f(h));                               \
            }                                                                      \
            *(s4v*)&Xh[row * 40 + kq] = hv;                                        \
            *(s4v*)&Xl[row * 40 + kq] = lv;                                        \
        }                                                                          \
        if (wload) {                                                               \
            int row = tid >> 2, kc = (tid & 3) * 8;                                \
            *(s8v*)&Wsh[row * 40 + kc] = wh;                                       \
            *(s8v*)&Wsl[row * 40 + kc] = wl;                                       \
        }                                                                          \
    }

static __device__ __forceinline__ void dual_mfma_body(
    unsigned char* lds, const float* __restrict__ X, int ldx,
    const unsigned short* __restrict__ Whi, const unsigned short* __restrict__ Wlo, int ldw,
    const float* __restrict__ bias,
    float* __restrict__ C, unsigned short* __restrict__ Ch, unsigned short* __restrict__ Cl,
    int ldc, unsigned char* __restrict__ maskOut, const unsigned char* __restrict__ maskMul,
    int K, int N, int mode, int m0, int n0)
{
    const int tid = threadIdx.x;
    unsigned short* Xh  = (unsigned short*)lds;            // 128*40 = 10240 B
    unsigned short* Xl  = (unsigned short*)(lds + 10240);  // 10240 B
    unsigned short* Wsh = (unsigned short*)(lds + 20480);  // 5120 B
    unsigned short* Wsl = (unsigned short*)(lds + 25600);  // 5120 B

    const int wave = tid >> 6, lane = tid & 63;
    const int q = lane >> 4, ln = lane & 15;
    const int wm = (wave & 3) * 32;
    const int wn = (wave >> 2) * 32;

    f4v acc[2][2];
    #pragma unroll
    for (int mt = 0; mt < 2; ++mt)
        #pragma unroll
        for (int nt = 0; nt < 2; ++nt)
            acc[mt][nt] = (f4v)(0.0f);

    float4 xr[2];
    s8v wh, wl;
    const bool wload = (tid < 256);

    DM_LOAD(0);
    DM_STASH();
    __syncthreads();

    for (int k0 = 0; k0 < K; k0 += 32) {
        bool last = (k0 + 32 >= K);
        if (!last) DM_LOAD(k0 + 32);

        s8v ah[2], al[2], bh[2], bl[2];
        #pragma unroll
        for (int mt = 0; mt < 2; ++mt) {
            int rowm = wm + mt * 16 + ln;
            ah[mt] = *(const s8v*)&Xh[rowm * 40 + q * 8];
            al[mt] = *(const s8v*)&Xl[rowm * 40 + q * 8];
        }
        #pragma unroll
        for (int nt = 0; nt < 2; ++nt) {
            int rown = wn + nt * 16 + ln;
            bh[nt] = *(const s8v*)&Wsh[rown * 40 + q * 8];
            bl[nt] = *(const s8v*)&Wsl[rown * 40 + q * 8];
        }
        #pragma unroll
        for (int mt = 0; mt < 2; ++mt)
            #pragma unroll
            for (int nt = 0; nt < 2; ++nt) {
                acc[mt][nt] = __builtin_amdgcn_mfma_f32_16x16x32_bf16(ah[mt], bh[nt], acc[mt][nt], 0, 0, 0);
                acc[mt][nt] = __builtin_amdgcn_mfma_f32_16x16x32_bf16(ah[mt], bl[nt], acc[mt][nt], 0, 0, 0);
                acc[mt][nt] = __builtin_amdgcn_mfma_f32_16x16x32_bf16(al[mt], bh[nt], acc[mt][nt], 0, 0, 0);
            }

        __syncthreads();
        if (!last) {
            DM_STASH();
            __syncthreads();
        }
    }

    mfma_epi(acc, bias, C, Ch, Cl, ldc, maskOut, maskMul, N, mode, m0, n0, wm, wn, q, ln);
}
#undef DM_LOAD
#undef DM_STASH

// ---- plane-input MFMA body (producer pre-split; staging is pure copies) ----
#define PP_LOAD(k0)                                                                \
    {                                                                              \
        int row = tid >> 2, kc = (tid & 3) * 8;                                    \
        xh8 = *(const s8v*)(Xhg + (size_t)(m0 + row) * ldx + (k0) + kc);           \
        xl8 = *(const s8v*)(Xlg + (size_t)(m0 + row) * ldx + (k0) + kc);           \
        if (wload) {                                                               \
            wh = *(const s8v*)(Whi + (size_t)(n0 + row) * ldw + (k0) + kc);        \
            wl = *(const s8v*)(Wlo + (size_t)(n0 + row) * ldw + (k0) + kc);        \
        }                                                                          \
    }
#define PP_STASH()                                                                 \
    {                                                                              \
        int row = tid >> 2, kc = (tid & 3) * 8;                                    \
        *(s8v*)&Xh[row * 40 + kc] = xh8;                                           \
        *(s8v*)&Xl[row * 40 + kc] = xl8;                                           \
        if (wload) {                                                               \
            *(s8v*)&Wsh[row * 40 + kc] = wh;                                       \
            *(s8v*)&Wsl[row * 40 + kc] = wl;                                       \
        }                                                                          \
    }

static __device__ __forceinline__ void pp_mfma_body(
    unsigned char* lds,
    const unsigned short* __restrict__ Xhg, const unsigned short* __restrict__ Xlg, int ldx,
    const unsigned short* __restrict__ Whi, const unsigned short* __restrict__ Wlo, int ldw,
    const float* __restrict__ bias,
    float* __restrict__ C, unsigned short* __restrict__ Ch, unsigned short* __restrict__ Cl,
    int ldc, unsigned char* __restrict__ maskOut, const unsigned char* __restrict__ maskMul,
    int K, int N, int mode, int m0, int n0)
{
    const int tid = threadIdx.x;
    unsigned short* Xh  = (unsigned short*)lds;            // 10240 B
    unsigned short* Xl  = (unsigned short*)(lds + 10240);  // 10240 B
    unsigned short* Wsh = (unsigned short*)(lds + 20480);  // 5120 B
    unsigned short* Wsl = (unsigned short*)(lds + 25600);  // 5120 B

    const int wave = tid >> 6, lane = tid & 63;
    const int q = lane >> 4, ln = lane & 15;
    const int wm = (wave & 3) * 32;
    const int wn = (wave >> 2) * 32;

    f4v acc[2][2];
    #pragma unroll
    for (int mt = 0; mt < 2; ++mt)
        #pragma unroll
        for (int nt = 0; nt < 2; ++nt)
            acc[mt][nt] = (f4v)(0.0f);

    s8v xh8, xl8, wh, wl;
    const bool wload = (tid < 256);

    PP_LOAD(0);
    PP_STASH();
    __syncthreads();

    for (int k0 = 0; k0 < K; k0 += 32) {
        bool last = (k0 + 32 >= K);
        if (!last) PP_LOAD(k0 + 32);

        s8v ah[2], al[2], bh[2], bl[2];
        #pragma unroll
        for (int mt = 0; mt < 2; ++mt) {
            int rowm = wm + mt * 16 + ln;
            ah[mt] = *(const s8v*)&Xh[rowm * 40 + q * 8];
            al[mt] = *(const s8v*)&Xl[rowm * 40 + q * 8];
        }
        #pragma unroll
        for (int nt = 0; nt < 2; ++nt) {
            int rown = wn + nt * 16 + ln;
            bh[nt] = *(const s8v*)&Wsh[rown * 40 + q * 8];
            bl[nt] = *(const s8v*)&Wsl[rown * 40 + q * 8];
        }
        #pragma unroll
        for (int mt = 0; mt < 2; ++mt)
            #pragma unroll
            for (int nt = 0; nt < 2; ++nt) {
                acc[mt][nt] = __builtin_amdgcn_mfma_f32_16x16x32_bf16(ah[mt], bh[nt], acc[mt][nt], 0, 0, 0);
                acc[mt][nt] = __builtin_amdgcn_mfma_f32_16x16x32_bf16(ah[mt], bl[nt], acc[mt][nt], 0, 0, 0);
                acc[mt][nt] = __builtin_amdgcn_mfma_f32_16x16x32_bf16(al[mt], bh[nt], acc[mt][nt], 0, 0, 0);
            }

        __syncthreads();
        if (!last) {
            PP_STASH();
            __syncthreads();
        }
    }

    mfma_epi(acc, bias, C, Ch, Cl, ldc, maskOut, maskMul, N, mode, m0, n0, wm, wn, q, ln);
}
#undef PP_LOAD
#undef PP_STASH

// ======== fused h0 + frag_pack: z=0 t-h0 fp32, z=1 z-h0 MFMA (plane-out), z=2 pack ========
__global__ __launch_bounds__(512) void h0_pack(
    const float* __restrict__ x, const float* __restrict__ Win,
    const unsigned short* __restrict__ WinH, const unsigned short* __restrict__ WinL,
    const float* __restrict__ bin, float* __restrict__ tA,
    unsigned short* __restrict__ zAh, unsigned short* __restrict__ zAl,
    const unsigned short* __restrict__ whi,
    unsigned short* __restrict__ WhF, unsigned short* __restrict__ WoF)
{
    __shared__ __align__(16) unsigned char lds[30720];
    const int m0 = blockIdx.x * 128, n0 = blockIdx.y * 64;
    int z = blockIdx.z;
    if (z == 0)
        dual_fp32_body(lds, x, 192, Win, 64, bin, tA, 512, 0, 0, 64, 512, 1 | 4, m0, n0);
    else if (z == 1)
        dual_mfma_body(lds, x + 128, 192, WinH, WinL, 64, bin, 0, zAh, zAl, 512, 0, 0,
                       64, 512, 1 | 32, m0, n0);
    else {
        int i = (blockIdx.y * 32 + blockIdx.x) * 512 + threadIdx.x;   // s8v slot
        if (i < 65536) {
            int lane = i & 63, ks = (i >> 6) & 31, g32 = (i >> 11) & 15, s = i >> 15;
            int row = g32 * 32 + (lane & 31);
            int k   = ks * 16 + (lane >> 5) * 8;
            const unsigned short* src = whi + 294912 + (size_t)s * 262144 + row * 512 + k;
            *(s8v*)(WhF + (size_t)i * 8) = *(const s8v*)src;
        } else if (i < 65536 + 4096) {
            int j = i - 65536;
            int lane = j & 63, ks = (j >> 6) & 31, g32 = j >> 11;
            int row = g32 * 32 + (lane & 31);
            int k   = ks * 16 + (lane >> 5) * 8;
            const unsigned short* src = whi + 819200 + row * 512 + k;
            *(s8v*)(WoF + (size_t)j * 8) = *(const s8v*)src;
        }
    }
}

// ======== h1: z=0 fp32 t (tA->tB), z=1 plane z (zA planes -> zB planes) ========
__global__ __launch_bounds__(512) void gemm_dualM(
    const float* __restrict__ X0,
    const unsigned short* __restrict__ X1h, const unsigned short* __restrict__ X1l,
    const float* __restrict__ W,
    const unsigned short* __restrict__ Whi, const unsigned short* __restrict__ Wlo,
    const float* __restrict__ bias,
    float* __restrict__ C0,
    unsigned short* __restrict__ C1h, unsigned short* __restrict__ C1l)
{
    __shared__ __align__(16) unsigned char lds[30720];
    const int m0 = blockIdx.x * 128, n0 = blockIdx.y * 64;
    if (blockIdx.z == 0)
        dual_fp32_body(lds, X0, 512, W, 512, bias, C0, 512, 0, 0, 512, 512, 1 | 2 | 4, m0, n0);
    else
        pp_mfma_body(lds, X1h, X1l, 512, Whi, Wlo, 512, bias, 0, C1h, C1l, 512, 0, 0,
                     512, 512, 1 | 2 | 32, m0, n0);
}

// ======== dual4: z=0 t-h(next) fp32, z=1 z-h(next) planes, z=2 t-delta, z=3 z-delta ====
__global__ __launch_bounds__(512) void gemm_dual4(
    const float* __restrict__ X0,
    const unsigned short* __restrict__ X1h, const unsigned short* __restrict__ X1l,
    const float* __restrict__ Wn, const float* __restrict__ Wd,
    const unsigned short* __restrict__ WnH, const unsigned short* __restrict__ WnL,
    const unsigned short* __restrict__ WdH, const unsigned short* __restrict__ WdL,
    const float* __restrict__ bn, const float* __restrict__ bd,
    float* __restrict__ C0,
    unsigned short* __restrict__ C1h, unsigned short* __restrict__ C1l,
    unsigned char* __restrict__ mot, unsigned char* __restrict__ moz)
{
    __shared__ __align__(16) unsigned char lds[30720];
    const int m0 = blockIdx.x * 128, n0 = blockIdx.y * 64;
    int z = blockIdx.z;
    if (z == 0)
        dual_fp32_body(lds, X0, 512, Wn, 512, bn, C0, 512, 0, 0, 512, 512, 1 | 2 | 4, m0, n0);
    else if (z == 2)
        dual_fp32_body(lds, X0, 512, Wd, 512, bd, 0, 512, mot, 0, 512, 512, 1 | 8, m0, n0);
    else if (z == 1)
        pp_mfma_body(lds, X1h, X1l, 512, WnH, WnL, 512, bn, 0, C1h, C1l, 512, 0, 0,
                     512, 512, 1 | 2 | 32, m0, n0);
    else
        pp_mfma_body(lds, X1h, X1l, 512, WdH, WdL, 512, bd, 0, 0, 0, 512, moz, 0,
                     512, 512, 1 | 8, m0, n0);
}

// ======== d3v1: z=0 t-delta3 fp32, z=1 z-delta3 planes, z=2 V1 (fp32-in, plane-out) ====
__global__ __launch_bounds__(512) void d3v1(
    const float* __restrict__ tB,
    const unsigned short* __restrict__ zBh, const unsigned short* __restrict__ zBl,
    const float* __restrict__ x,
    const float* __restrict__ Wh2,
    const unsigned short* __restrict__ Wh2H, const unsigned short* __restrict__ Wh2L,
    const unsigned short* __restrict__ G0hi, const unsigned short* __restrict__ G0lo,
    const float* __restrict__ bh2,
    unsigned short* __restrict__ tAh, unsigned short* __restrict__ tAl,
    unsigned char* __restrict__ mt3, unsigned char* __restrict__ mz3,
    const unsigned char* __restrict__ mt1)
{
    __shared__ __align__(16) unsigned char lds[30720];
    const int m0 = blockIdx.x * 128, n0 = blockIdx.y * 64;
    int z = blockIdx.z;
    if (z == 0)
        dual_fp32_body(lds, tB, 512, Wh2, 512, bh2, 0, 512, mt3, 0, 512, 512, 1 | 8, m0, n0);
    else if (z == 1)
        pp_mfma_body(lds, zBh, zBl, 512, Wh2H, Wh2L, 512, bh2, 0, 0, 0, 512, mz3, 0,
                     512, 512, 1 | 8, m0, n0);
    else
        dual_mfma_body(lds, x + 64, 192, G0hi, G0lo, 64, 0, 0, tAh, tAl, 512, 0, mt1,
                       64, 512, 32 | 16, m0, n0);
}

// ======== V3: plane-in, plane-out, mask-mul ========
__global__ __launch_bounds__(512) void gemm_v3(
    const unsigned short* __restrict__ Xh, const unsigned short* __restrict__ Xl,
    const unsigned short* __restrict__ Whi, const unsigned short* __restrict__ Wlo,
    unsigned short* __restrict__ Ch, unsigned short* __restrict__ Cl,
    const unsigned char* __restrict__ maskMul)
{
    __shared__ __align__(16) unsigned char lds[30720];
    pp_mfma_body(lds, Xh, Xl, 512, Whi, Wlo, 512, 0, 0, Ch, Cl, 512, 0, maskMul,
                 512, 512, 32 | 16, blockIdx.x * 128, blockIdx.y * 64);
}

// ======== finals: z=0 h_out (fp32-in tB -> out), z=1 h_dot (planes zB -> out+64) ========
__global__ __launch_bounds__(512) void gemm_mm(
    const float* __restrict__ tB,
    const unsigned short* __restrict__ zBh, const unsigned short* __restrict__ zBl,
    const unsigned short* __restrict__ Whi, const unsigned short* __restrict__ Wlo,
    const float* __restrict__ bias, float* __restrict__ out)
{
    __shared__ __align__(16) unsigned char lds[30720];
    const int m0 = blockIdx.x * 128, n0 = blockIdx.y * 64;
    if (blockIdx.z == 0)
        dual_mfma_body(lds, tB, 512, Whi, Wlo, 512, bias, out, 0, 0, 192, 0, 0,
                       512, 64, 1 | 4, m0, n0);
    else
        pp_mfma_body(lds, zBh, zBl, 512, Whi, Wlo, 512, 0, out + 64, 0, 0, 192, 0, 0,
                     512, 64, 4, m0, n0);
}

// ---------- zng (R19-validated, 1 elem/block, 2 blocks/CU) + V2 tail (plane body) ----------
__global__ __launch_bounds__(512, 4) void zng_v2(
    const unsigned short* __restrict__ WhF,    // [2][16][32][64][8] frag-packed Wh1,Wh2
    const unsigned short* __restrict__ WoF,    // [2][32][64][8] frag-packed Wout
    const unsigned short* __restrict__ G0F,    // [32][2][64][8] frag-packed G0
    const unsigned char* __restrict__ mz1,
    const unsigned char* __restrict__ mz2,
    const unsigned char* __restrict__ mz3,
    float* __restrict__ out,                   // (4096,192), writes cols 128..191
    const unsigned short* __restrict__ tAh, const unsigned short* __restrict__ tAl,
    const unsigned short* __restrict__ Wh1H, const unsigned short* __restrict__ Wh1L,
    const unsigned char* __restrict__ mt2,
    unsigned short* __restrict__ zAh, unsigned short* __restrict__ zAl)
{
    __shared__ __align__(16) unsigned char ldsb[66560];

    if (blockIdx.x >= 4096) {
        int idx = blockIdx.x - 4096;           // 0..255: V2 = mask2 (.) (V1 @ Wh1^T)
        pp_mfma_body(ldsb, tAh, tAl, 512, Wh1H, Wh1L, 512, 0, 0, zAh, zAl, 512, 0, mt2,
                     512, 512, 32 | 16, (idx & 31) * 128, (idx >> 5) * 64);
        return;
    }

    unsigned short* RtF = (unsigned short*)ldsb;            // 65536 B, fragment order
    unsigned char* m2s = ldsb + 65536;                      // 512 B
    unsigned char* m3s = ldsb + 66048;                      // 512 B

    const int b0  = blockIdx.x;     // one batch element per block
    const int tid = threadIdx.x;

    m2s[tid] = mz2[(size_t)b0 * 512 + tid];
    m3s[tid] = mz3[(size_t)b0 * 512 + tid];

    // ---- setup: RtF = frag(mask1 (.) G0^T); coalesced read + linear LDS write ----
    #pragma unroll
    for (int it = 0; it < 8; ++it) {
        int sl = it * 512 + tid;           // fragment slot 0..4095
        int ls = sl & 63;                  // lane within fragment
        int ks = sl >> 7;                  // k-step
        int k0 = ks * 16 + (ls >> 5) * 8;  // first k of this lane's 8 elems
        s8v g = *(const s8v*)(G0F + (size_t)sl * 8);
        const unsigned char* mm = mz1 + (size_t)b0 * 512 + k0;
        unsigned int mlo = *(const unsigned int*)(mm);
        unsigned int mhi = *(const unsigned int*)(mm + 4);
        s8v r;
        #pragma unroll
        for (int j = 0; j < 4; ++j) r[j] = ((mlo >> (8 * j)) & 1) ? g[j] : (short)0;
        #pragma unroll
        for (int j = 0; j < 4; ++j) r[4 + j] = ((mhi >> (8 * j)) & 1) ? g[4 + j] : (short)0;
        *(s8v*)(&RtF[(size_t)sl * 8]) = r;
    }
    __syncthreads();

    const int lane = tid & 63, wave = tid >> 6;
    const int l31 = lane & 31, h = lane >> 5;

    // ---- 2 chained layers: R <- mask (.) (Wh @ R) ----
    for (int s = 0; s < 2; ++s) {
        const unsigned short* Ar0 = WhF + (size_t)s * 262144
                                  + (size_t)(wave * 2) * 16384 + lane * 8;
        const unsigned short* Ar1 = Ar0 + 16384;

        f16v acc[2][2];
        #pragma unroll
        for (int mt = 0; mt < 2; ++mt)
            #pragma unroll
            for (int nt = 0; nt < 2; ++nt)
                acc[mt][nt] = (f16v)(0.0f);

        // 2-deep A prefetch (L2 ~200cyc), 1-deep B prefetch (LDS)
        s8v a0A = *(const s8v*)(Ar0);
        s8v a1A = *(const s8v*)(Ar1);
        s8v a0B = *(const s8v*)(Ar0 + 512);
        s8v a1B = *(const s8v*)(Ar1 + 512);
        s8v b0c = *(const s8v*)&RtF[lane * 8];
        s8v b1c = *(const s8v*)&RtF[512 + lane * 8];

        #pragma unroll 4
        for (int ks = 0; ks < 32; ++ks) {
            int kf = ((ks + 2) & 31) * 512;           // A: wraps; redundant tail loads
            s8v a0N = *(const s8v*)(Ar0 + kf);
            s8v a1N = *(const s8v*)(Ar1 + kf);
            int kb = ((ks + 1) & 31) * 1024;          // B: fragment-linear
            s8v b0n = *(const s8v*)&RtF[kb + lane * 8];
            s8v b1n = *(const s8v*)&RtF[kb + 512 + lane * 8];

            __builtin_amdgcn_s_setprio(1);
            acc[0][0] = __builtin_amdgcn_mfma_f32_32x32x16_bf16(a0A, b0c, acc[0][0], 0, 0, 0);
            acc[0][1] = __builtin_amdgcn_mfma_f32_32x32x16_bf16(a0A, b1c, acc[0][1], 0, 0, 0);
            acc[1][0] = __builtin_amdgcn_mfma_f32_32x32x16_bf16(a1A, b0c, acc[1][0], 0, 0, 0);
            acc[1][1] = __builtin_amdgcn_mfma_f32_32x32x16_bf16(a1A, b1c, acc[1][1], 0, 0, 0);
            __builtin_amdgcn_s_setprio(0);

            a0A = a0B; a0B = a0N;
            a1A = a1B; a1B = a1N;
            b0c = b0n; b1c = b1n;
        }
        __syncthreads();

        // ---- epilogue: mask, pack bf16, write new RtF (fragment order, conflict-free) ----
        const unsigned char* msk = (s == 0) ? m2s : m3s;
        #pragma unroll
        for (int mt = 0; mt < 2; ++mt) {
            #pragma unroll
            for (int g = 0; g < 4; ++g) {
                int kk = wave * 64 + mt * 32 + g * 8 + h * 4;   // output k-row base
                int ks = wave * 4 + mt * 2 + (g >> 1);
                int khalf = g & 1;
                uchar4 mv = *(const uchar4*)&msk[kk];
                unsigned char mb[4] = {mv.x, mv.y, mv.z, mv.w};
                #pragma unroll
                for (int nt = 0; nt < 2; ++nt) {
                    s4v pk;
                    #pragma unroll
                    for (int r = 0; r < 4; ++r) {
                        float v = mb[r] ? acc[mt][nt][g * 4 + r] : 0.0f;
                        pk[r] = (short)f2bf(v);
                    }
                    *(s4v*)(&RtF[(ks * 2 + nt) * 512 + (l31 + 32 * khalf) * 8 + h * 4]) = pk;
                }
            }
        }
        __syncthreads();
    }

    // ---- final: Wout @ R, row norms; waves 0-1 only (no barriers below) ----
    if (wave < 2) {
        const unsigned short* Wr = WoF + wave * 16384 + lane * 8;
        f16v a3[2];
        a3[0] = (f16v)(0.0f);
        a3[1] = (f16v)(0.0f);
        #pragma unroll 2
        for (int ks = 0; ks < 32; ++ks) {
            s8v af = *(const s8v*)(Wr + ks * 512);
            s8v bb0 = *(const s8v*)&RtF[ks * 1024 + lane * 8];
            s8v bb1 = *(const s8v*)&RtF[ks * 1024 + 512 + lane * 8];
            a3[0] = __builtin_amdgcn_mfma_f32_32x32x16_bf16(af, bb0, a3[0], 0, 0, 0);
            a3[1] = __builtin_amdgcn_mfma_f32_32x32x16_bf16(af, bb1, a3[1], 0, 0, 0);
        }
        float sq[16];
        #pragma unroll
        for (int i = 0; i < 16; ++i) {
            float v0 = a3[0][i], v1 = a3[1][i];
            sq[i] = fmaf(v0, v0, v1 * v1);
        }
        #pragma unroll
        for (int off = 1; off < 32; off <<= 1)
            #pragma unroll
            for (int i = 0; i < 16; ++i)
                sq[i] += __shfl_xor(sq[i], off, 64);
        if (l31 == 0) {
            #pragma unroll
            for (int g = 0; g < 4; ++g)
                #pragma unroll
                for (int r = 0; r < 4; ++r)
                    out[(size_t)b0 * 192 + 128 + wave * 32 + g * 8 + h * 4 + r] = sqrtf(sq[g * 4 + r]);
        }
    }
}

// ---------- host ----------
extern "C" void kernel_launch(void* const* d_in, const int* in_sizes, int n_in,
                              void* d_out, int out_size, void* d_ws, size_t ws_size,
                              hipStream_t stream) {
    const float* x    = (const float*)d_in[0];
    const float* Win  = (const float*)d_in[1];
    const float* bin  = (const float*)d_in[2];
    const float* Wh   = (const float*)d_in[3];
    const float* bh   = (const float*)d_in[4];
    const float* Wout = (const float*)d_in[5];
    const float* bout = (const float*)d_in[6];
    float* out = (float*)d_out;

    char* ws = (char*)d_ws;
    unsigned short* whi  = (unsigned short*)(ws);                   // 1703936 B
    unsigned short* wlo  = (unsigned short*)(ws + 1703936);         // 1703936 B
    unsigned short* G0hi = (unsigned short*)(ws + 3407872);         // 65536 B
    unsigned short* G0lo = (unsigned short*)(ws + 3473408);         // 65536 B
    unsigned short* G0F  = (unsigned short*)(ws + 3538944);         // 65536 B (frag-packed)
    unsigned char*  masks = (unsigned char*)(ws + 3604480);         // 6 * 2 MB
    unsigned char* mt1 = masks + 0 * 2097152;
    unsigned char* mt2 = masks + 1 * 2097152;
    unsigned char* mt3 = masks + 2 * 2097152;
    unsigned char* mz1 = masks + 3 * 2097152;
    unsigned char* mz2 = masks + 4 * 2097152;
    unsigned char* mz3 = masks + 5 * 2097152;
    float* bufs = (float*)(ws + 3604480 + 12582912);                // 4 x 8 MB slots
    float* tA = bufs + 0 * 2097152;                                 // t fp32 / V1 planes
    float* tB = bufs + 1 * 2097152;                                 // t fp32
    // z-chain plane pairs (hi|lo) in slots 2 and 3:
    unsigned short* zAh = (unsigned short*)(bufs + 2 * 2097152);
    unsigned short* zAl = zAh + 2097152;
    unsigned short* zBh = (unsigned short*)(bufs + 3 * 2097152);
    unsigned short* zBl = zBh + 2097152;
    // V1 plane pair aliases slot 0 (tA dead for t-chain by then):
    unsigned short* tAh = (unsigned short*)tA;
    unsigned short* tAl = tAh + 2097152;
    unsigned short* WhF = (unsigned short*)(ws + 49741824);         // 1048576 B
    unsigned short* WoF = (unsigned short*)(ws + 50790400);         // 65536 B

    // hi/lo plane offsets (elems): [Win@0 | Wh0@32768 | Wh1@294912 | Wh2@557056 | Wout@819200]
    const unsigned short* WinH  = whi,          *WinL  = wlo;
    const unsigned short* Wh0H  = whi + 32768,  *Wh0L  = wlo + 32768;
    const unsigned short* Wh1H  = whi + 294912, *Wh1L  = wlo + 294912;
    const unsigned short* Wh2H  = whi + 557056, *Wh2L  = wlo + 557056;
    const unsigned short* WoutH = whi + 819200, *WoutL = wlo + 819200;

    const float* Wh0 = Wh;
    const float* Wh1 = Wh + 262144;
    const float* Wh2 = Wh + 524288;
    const float* bh0 = bh, *bh1 = bh + 512, *bh2 = bh + 1024;

    // ---- setup ----
    conv_g0<<<dim3(3456), dim3(256), 0, stream>>>(Win, Wh, Wout, whi, wlo, G0hi, G0lo, G0F);
    h0_pack<<<dim3(32, 8, 3), dim3(512), 0, stream>>>(x, Win, WinH, WinL, bin, tA, zAh, zAl,
                                                      whi, WhF, WoF);                          // h0 + pack

    // ---- forward + delta chain (t fp32 for mask fidelity; z split-bf16 planes) ----
    gemm_dualM<<<dim3(32, 8, 2), dim3(512), 0, stream>>>(tA, zAh, zAl, Wh0, Wh0H, Wh0L, bh0,
                                                         tB, zBh, zBl);                        // h1
    gemm_dual4<<<dim3(32, 8, 4), dim3(512), 0, stream>>>(tB, zBh, zBl, Wh1, Wh0,
                                                         Wh1H, Wh1L, Wh0H, Wh0L, bh1, bh0,
                                                         tA, zAh, zAl, mt1, mz1);              // h2 + delta1
    gemm_dual4<<<dim3(32, 8, 4), dim3(512), 0, stream>>>(tA, zAh, zAl, Wh2, Wh1,
                                                         Wh2H, Wh2L, Wh1H, Wh1L, bh2, bh1,
                                                         tB, zBh, zBl, mt2, mz2);              // h3 + delta2
    d3v1<<<dim3(32, 8, 3), dim3(512), 0, stream>>>(tB, zBh, zBl, x, Wh2, Wh2H, Wh2L,
                                                   G0hi, G0lo, bh2, tAh, tAl,
                                                   mt3, mz3, mt1);                             // delta3 + V1

    // ---- zng (4096 blocks) + V2 (256 tail blocks: tA planes -> zA planes) ----
    zng_v2<<<dim3(4352), dim3(512), 0, stream>>>(WhF, WoF, G0F, mz1, mz2, mz3, out,
                                                 tAh, tAl, Wh1H, Wh1L, mt2, zAh, zAl);

    // ---- V3: zA planes -> zB planes ----
    gemm_v3<<<dim3(32, 8), dim3(512), 0, stream>>>(zAh, zAl, Wh2H, Wh2L, zBh, zBl, mt3);

    // ---- finals: h_out (tB fp32 -> out cols 0..63) + h_dot (zB planes -> cols 64..127) ----
    gemm_mm<<<dim3(32, 1, 2), dim3(512), 0, stream>>>(tB, zBh, zBl, WoutH, WoutL, bout, out);
}